// Round 3
// baseline (344.296 us; speedup 1.0000x reference)
//
#include <hip/hip_runtime.h>
#include <hip/hip_bf16.h>

// Problem constants (B=32, S=512, F=32, H=8, D=300, FH=32)
#define NB 32
#define NS 512
#define NF 32
#define NH 8
#define ND 300
#define NTOK (NB*NS)      // 16384 tokens
#define TPW 8             // tokens per wave-job (both waves see all 8 tokens)
#define WPB 2             // waves per block, cooperating on the SAME 8 tokens
#define TPB 8             // tokens per block -> grid 2048 = 4096 waves = 16 waves/CU
                          // (R12: wave COUNT was the cap: TPW=8 over 1024 blocks gave
                          //  only 2048 waves = 8/CU regardless of packaging. Feature-split
                          //  doubles waves without shrinking TPW/raising VGPR.)

#define L2E 1.4426950408889634f

using bf16 = __hip_bfloat16;
typedef float v2f __attribute__((ext_vector_type(2)));

__device__ __forceinline__ float rcpf_(float x){ return __builtin_amdgcn_rcpf(x); }
__device__ __forceinline__ float rsqf_(float x){ return __builtin_amdgcn_rsqf(x); }
__device__ __forceinline__ float sigm(float x){ return rcpf_(1.0f + __expf(-x)); }
// gate-B coefficients are pre-scaled by log2(e) in precompute -> exp2 directly
__device__ __forceinline__ float sigm2(float x){ return rcpf_(1.0f + __builtin_amdgcn_exp2f(-x)); }
__device__ __forceinline__ float eluf(float x){ return x > 0.0f ? x : __expf(x) - 1.0f; }

// packed fp32 FMA -> v_pk_fma_f32
__device__ __forceinline__ v2f fma2(v2f a, v2f b, v2f c){
    return __builtin_elementwise_fma(a, b, c);
}
__device__ __forceinline__ v2f fma2s(float s, v2f b, v2f c){
    return __builtin_elementwise_fma((v2f){s, s}, b, c);
}

template<int BF16>
__device__ __forceinline__ float ldf(const void* p, size_t i){
    if (BF16) return __bfloat162float(((const bf16*)p)[i]);
    return ((const float*)p)[i];
}
template<int BF16>
__device__ __forceinline__ void stf(void* p, size_t i, float v){
    if (BF16) ((bf16*)p)[i] = __float2bfloat16(v);
    else      ((float*)p)[i] = v;
}

// dtype test on a known-ones tensor: bf16 pair -> 0x3F803F80, fp32 -> 0x3F800000
__device__ __forceinline__ bool is_bf16(const void* ones){
    return *(const unsigned*)ones == 0x3F803F80u;
}

// bf16 pair (lo,hi) -> v2f {lo,hi}: 2 VALU ops
__device__ __forceinline__ v2f unpk(unsigned u){
    return (v2f){ __int_as_float((int)(u << 16)),
                  __int_as_float((int)(u & 0xFFFF0000u)) };
}
__device__ __forceinline__ unsigned pack_bf(float a, float b){
    bf16 ha = __float2bfloat16(a), hb = __float2bfloat16(b);
    return (unsigned)*(unsigned short*)&ha | ((unsigned)*(unsigned short*)&hb << 16);
}

// ---------------- DPP reductions (VALU pipe — keeps the LDS pipe free) ------
template<int CTRL>
__device__ __forceinline__ float dppadd(float v){
    return v + __int_as_float(__builtin_amdgcn_update_dpp(
        0, __float_as_int(v), CTRL, 0xF, 0xF, true));
}
template<int CTRL>
__device__ __forceinline__ float dppmax(float v){
    return fmaxf(v, __int_as_float(__builtin_amdgcn_update_dpp(
        __float_as_int(v), __float_as_int(v), CTRL, 0xF, 0xF, false)));
}
__device__ __forceinline__ float rlane(float v, int l){
    return __int_as_float(__builtin_amdgcn_readlane(__float_as_int(v), l));
}
__device__ __forceinline__ float wsum64(float v){
    v = dppadd<0x111>(v); v = dppadd<0x112>(v); v = dppadd<0x114>(v); v = dppadd<0x118>(v);
    v = dppadd<0x142>(v); v = dppadd<0x143>(v);
    return rlane(v, 63);
}
__device__ __forceinline__ float rsum32(float v){
    v = dppadd<0x111>(v); v = dppadd<0x112>(v); v = dppadd<0x114>(v); v = dppadd<0x118>(v);
    return rlane(v, 15) + rlane(v, 31);
}
__device__ __forceinline__ float rmax32(float v){
    v = dppmax<0x111>(v); v = dppmax<0x112>(v); v = dppmax<0x114>(v); v = dppmax<0x118>(v);
    return fmaxf(rlane(v, 15), rlane(v, 31));
}

// ---------------------------------------------------------------------------
// Precompute packed rows of 16 dwords (= one 64B line) per (f,d):
//   dword 0..7 : bf16 pair (lo=A_k, hi=B_k*log2e), k=0..7   [gate coeffs, folded fc2]
//   dword 8    : bcA (fp32)   dword 9: bcB*log2e (fp32)
//   dword 10,11: sg_ln_g, sg_ln_b (fp32)
//   dword 12,13: rw, rb (fp32)  [R12: residual folded to x*rw+rb —
//                interp(pre) = interp(x*pw+pb) = x*interp(pw)+interp(pb);
//                kills 2 LDS reads + 2 VALU per element in the hot i-loop]
//   dword 14,15: pad
// ---------------------------------------------------------------------------
template<int BF16>
__device__ void precompute_body(const void* __restrict__ W2, const void* __restrict__ b2,
                                const void* __restrict__ Wg, const void* __restrict__ bg,
                                const void* __restrict__ sg_g, const void* __restrict__ sg_b,
                                const void* __restrict__ pre_w, const void* __restrict__ pre_b,
                                unsigned* __restrict__ Crow,
                                float* __restrict__ w2t, float* __restrict__ b2s,
                                float (*part)[64][18])
{
    const int tid  = threadIdx.x;
    const int lane = tid & 63;
    const int wv   = tid >> 6;            // 0..7: m-chunk
    const int f    = blockIdx.x & 31;     // 160 blocks = 32 f x 5 d-chunks
    const int c    = blockIdx.x >> 5;     // 0..4
    const int d    = c * 64 + lane;       // 0..319 (chunk 4 partially masked)
    const int dc   = d < 299 ? d : 299;   // clamp for loads (keeps Wg in-bounds)

    // stage W2 transposed [m][k] (fp32) + b2 for this f
    for (int idx = tid; idx < 2400; idx += 512) {
        int m = idx >> 3, k = idx & 7;
        w2t[idx] = ldf<BF16>(W2, (size_t)f * 2400 + (size_t)k * 300 + m);
    }
    if (tid < 300) b2s[tid] = ldf<BF16>(b2, (size_t)f * 300 + tid);
    __syncthreads();

    v2f aA01 = {0,0}, aA23 = {0,0}, aA45 = {0,0}, aA67 = {0,0};
    v2f aB01 = {0,0}, aB23 = {0,0}, aB45 = {0,0}, aB67 = {0,0};
    float bAa = 0.f, bBa = 0.f;

    const int m0 = (wv * 300) >> 3;
    const int m1 = ((wv + 1) * 300) >> 3;
    const size_t WgF = (size_t)f * 180000 + dc;
    #pragma unroll 4
    for (int m = m0; m < m1; ++m) {
        float wa = ldf<BF16>(Wg, WgF + (size_t)m * 600);        // coalesced across lanes
        float wb = ldf<BF16>(Wg, WgF + (size_t)m * 600 + 300);  // coalesced across lanes
        float4 wk0 = *(const float4*)(w2t + m * 8);             // k0..3 (broadcast)
        float4 wk1 = *(const float4*)(w2t + m * 8 + 4);         // k4..7 (broadcast)
        aA01 = fma2s(wa, (v2f){wk0.x, wk0.y}, aA01);
        aA23 = fma2s(wa, (v2f){wk0.z, wk0.w}, aA23);
        aA45 = fma2s(wa, (v2f){wk1.x, wk1.y}, aA45);
        aA67 = fma2s(wa, (v2f){wk1.z, wk1.w}, aA67);
        aB01 = fma2s(wb, (v2f){wk0.x, wk0.y}, aB01);
        aB23 = fma2s(wb, (v2f){wk0.z, wk0.w}, aB23);
        aB45 = fma2s(wb, (v2f){wk1.x, wk1.y}, aB45);
        aB67 = fma2s(wb, (v2f){wk1.z, wk1.w}, aB67);
        float b2v = b2s[m];
        bAa += b2v * wa;
        bBa += b2v * wb;
    }

    {
        float* p = part[wv][lane];
        p[0]  = aA01.x; p[1]  = aA01.y; p[2]  = aA23.x; p[3]  = aA23.y;
        p[4]  = aA45.x; p[5]  = aA45.y; p[6]  = aA67.x; p[7]  = aA67.y;
        p[8]  = aB01.x; p[9]  = aB01.y; p[10] = aB23.x; p[11] = aB23.y;
        p[12] = aB45.x; p[13] = aB45.y; p[14] = aB67.x; p[15] = aB67.y;
        p[16] = bAa;    p[17] = bBa;
    }
    __syncthreads();

    if (tid < 64 && d < 300) {
        float s[18];
        #pragma unroll
        for (int v = 0; v < 18; ++v) {
            float t0 = part[0][lane][v] + part[1][lane][v];
            float t1 = part[2][lane][v] + part[3][lane][v];
            float t2 = part[4][lane][v] + part[5][lane][v];
            float t3 = part[6][lane][v] + part[7][lane][v];
            s[v] = (t0 + t1) + (t2 + t3);
        }
        unsigned dw[12];
        #pragma unroll
        for (int k = 0; k < 8; ++k) dw[k] = pack_bf(s[k], s[8 + k] * L2E);
        dw[8]  = __float_as_uint(s[16] + ldf<BF16>(bg, (size_t)f * 600 + d));
        dw[9]  = __float_as_uint((s[17] + ldf<BF16>(bg, (size_t)f * 600 + d + 300)) * L2E);
        dw[10] = __float_as_uint(ldf<BF16>(sg_g, (size_t)f * 300 + d));
        dw[11] = __float_as_uint(ldf<BF16>(sg_b, (size_t)f * 300 + d));

        // residual fold: rw = interp(pre_w[f,:]) at d, rb = interp(pre_b[f,:])
        float pos = (float)d * (7.0f / 299.0f);
        int lo = (int)floorf(pos); lo = lo < 0 ? 0 : (lo > 6 ? 6 : lo);
        float fr = pos - (float)lo;
        float pwl = ldf<BF16>(pre_w, (size_t)f * 8 + lo);
        float pwh = ldf<BF16>(pre_w, (size_t)f * 8 + lo + 1);
        float pbl = ldf<BF16>(pre_b, (size_t)f * 8 + lo);
        float pbh = ldf<BF16>(pre_b, (size_t)f * 8 + lo + 1);
        unsigned rwu = __float_as_uint(pwl + fr * (pwh - pwl));
        unsigned rbu = __float_as_uint(pbl + fr * (pbh - pbl));

        unsigned* row = Crow + (size_t)(f * 300 + d) * 16;
        *(uint4*)(row + 0)  = make_uint4(dw[0], dw[1], dw[2],  dw[3]);
        *(uint4*)(row + 4)  = make_uint4(dw[4], dw[5], dw[6],  dw[7]);
        *(uint4*)(row + 8)  = make_uint4(dw[8], dw[9], dw[10], dw[11]);
        *(uint4*)(row + 12) = make_uint4(rwu, rbu, 0u, 0u);
    }
}

__global__ void precompute_kernel(const void* __restrict__ W2, const void* __restrict__ b2,
                                  const void* __restrict__ Wg, const void* __restrict__ bg,
                                  const void* __restrict__ sg_g, const void* __restrict__ sg_b,
                                  const void* __restrict__ pre_w, const void* __restrict__ pre_b,
                                  unsigned* __restrict__ Crow)
{
    __shared__ float w2t[2400];          // W2 transposed [m][k], fp32
    __shared__ float b2s[300];
    __shared__ float part[8][64][18];    // per-wave partials
    if (is_bf16(sg_g))   // sg_ln_g is ones
        precompute_body<1>(W2, b2, Wg, bg, sg_g, sg_b, pre_w, pre_b, Crow, w2t, b2s, part);
    else
        precompute_body<0>(W2, b2, Wg, bg, sg_g, sg_b, pre_w, pre_b, Crow, w2t, b2s, part);
}

// ---------------------------------------------------------------------------
// Main kernel (R12 feature-split): block = 8 tokens x 2 waves. Wave w stages
// tokens [w*4, w*4+4) (Stage A+H), then both waves run Stage B redundantly
// (full 8 tokens — needed for their own softmax-weight registers), then the
// feature loop is SPLIT: wave0 does f=0..15, wave1 f=16..31, acc merged via
// LDS at the end. 4096 waves total = 16 waves/CU (was 8: TPW=8 with a
// f-unsplit loop caps waves at NTOK/8=2048). Residual now x*rw+rb from the
// Crow table (no preS reads in the hot loop), so preS is dead after Stage B
// and reused as the acc-merge buffer.
// ---------------------------------------------------------------------------
template<int BF16>
__device__ void vsn_body(const void* __restrict__ x,
                         const void* __restrict__ pre_w, const void* __restrict__ pre_b,
                         const void* __restrict__ W1,    const void* __restrict__ b1,
                         const void* __restrict__ fl1w,  const void* __restrict__ fl1b,
                         const void* __restrict__ fl2w,  const void* __restrict__ fl2b,
                         const void* __restrict__ flgw,  const void* __restrict__ flgb,
                         const void* __restrict__ flng,  const void* __restrict__ flnb,
                         const unsigned* __restrict__ Crow,
                         void* __restrict__ d_out, float* preS, unsigned* hS)
{
    void* outMain = d_out;                                             // [B,S,D]
    void* outW    = (char*)d_out + (size_t)NTOK * ND * (BF16 ? 2 : 4); // [B,S,1,F]

    const int tid   = threadIdx.x;
    const int wave  = tid >> 6;
    const int lane  = tid & 63;
    const int tokBase = blockIdx.x * TPB;       // block's 8 tokens (shared)
    const int tA0   = wave * (TPB / WPB);       // staging slice: 4 tokens
    const int fBase = wave * (NF / WPB);        // compute slice: 16 features

    // ---- x residual registers: xrA holds x[tok=lane&7, f=fBase+(lane>>3)] ----
    {
    }
    const int tx = lane & 7, fo = lane >> 3;
    float xrA = ldf<BF16>(x, (size_t)(tokBase + tx) * NF + fBase + fo);
    float xrB = ldf<BF16>(x, (size_t)(tokBase + tx) * NF + fBase + 8 + fo);

    // ---- Stage A (t-split): pre = x*pre_w + pre_b ----
    {
        float pw[4], pb[4];
        #pragma unroll
        for (int q = 0; q < 4; ++q) {
            pw[q] = ldf<BF16>(pre_w, 4 * lane + q);
            pb[q] = ldf<BF16>(pre_b, 4 * lane + q);
        }
        const int fidx = lane >> 1;
        #pragma unroll
        for (int j = 0; j < TPB / WPB; ++j) {
            int t = tA0 + j;
            float xv = ldf<BF16>(x, (size_t)(tokBase + t) * NF + fidx);
            float4 v;
            v.x = xv * pw[0] + pb[0];
            v.y = xv * pw[1] + pb[1];
            v.z = xv * pw[2] + pb[2];
            v.w = xv * pw[3] + pb[3];
            *(float4*)(&preS[t * 256 + 4 * lane]) = v;
        }
    }

    // ---- Stage H (t-split): h = elu(pre @ W1 + b1), stored bf16-packed ----
    {
        const int f  = lane >> 1;
        const int kh = (lane & 1) * 4;
        float w1r[8][4], b1r[4];
        #pragma unroll
        for (int m = 0; m < 8; ++m)
            #pragma unroll
            for (int q = 0; q < 4; ++q)
                w1r[m][q] = ldf<BF16>(W1, (size_t)(f * 8 + m) * 8 + kh + q);
        #pragma unroll
        for (int q = 0; q < 4; ++q) b1r[q] = ldf<BF16>(b1, f * 8 + kh + q);

        #pragma unroll
        for (int j = 0; j < TPB / WPB; ++j) {
            int t = tA0 + j;
            float pr[8];
            float4 pA = *(const float4*)(&preS[t * 256 + f * 8]);
            float4 pB = *(const float4*)(&preS[t * 256 + f * 8 + 4]);
            pr[0]=pA.x; pr[1]=pA.y; pr[2]=pA.z; pr[3]=pA.w;
            pr[4]=pB.x; pr[5]=pB.y; pr[6]=pB.z; pr[7]=pB.w;
            float a[4] = {b1r[0], b1r[1], b1r[2], b1r[3]};
            #pragma unroll
            for (int m = 0; m < 8; ++m)
                #pragma unroll
                for (int q = 0; q < 4; ++q)
                    a[q] += pr[m] * w1r[m][q];
            uint2 hp;
            hp.x = pack_bf(eluf(a[0]), eluf(a[1]));
            hp.y = pack_bf(eluf(a[2]), eluf(a[3]));
            *(uint2*)(&hS[t * 128 + 2 * lane]) = hp;    // dwords 2l,2l+1 = cols 4l..4l+3
        }
    }
    __syncthreads();   // staging complete (preS + hS for all 8 tokens)

    // ---- Stage B: flattened GRN -> softmax weights (all 8 tokens, redundant
    //      in both waves — each needs the full wreg for rlane(wreg[t], f)) ----
    const int jj = lane & 31;
    const int hB = lane >> 5;
    float wreg[TPW];
    {
        float f1b = (hB == 0) ? ldf<BF16>(fl1b, jj) : 0.0f;
        v2f p1v[TPW / 2];
        #pragma unroll
        for (int g = 0; g < TPW / 2; ++g) p1v[g] = (v2f){f1b, f1b};
        for (int kg = 0; kg < 32; ++kg) {
            const int kk = hB * 128 + kg * 4;
            float4 pr[TPW];
            #pragma unroll
            for (int t = 0; t < TPW; ++t)
                pr[t] = *(const float4*)(&preS[t * 256 + kk]);
            float w0 = ldf<BF16>(fl1w, (size_t)(kk + 0) * 32 + jj);
            float w1 = ldf<BF16>(fl1w, (size_t)(kk + 1) * 32 + jj);
            float w2 = ldf<BF16>(fl1w, (size_t)(kk + 2) * 32 + jj);
            float w3 = ldf<BF16>(fl1w, (size_t)(kk + 3) * 32 + jj);
            #pragma unroll
            for (int g = 0; g < TPW / 2; ++g) {
                p1v[g] = fma2((v2f){pr[2*g].x, pr[2*g+1].x}, (v2f){w0, w0}, p1v[g]);
                p1v[g] = fma2((v2f){pr[2*g].y, pr[2*g+1].y}, (v2f){w1, w1}, p1v[g]);
                p1v[g] = fma2((v2f){pr[2*g].z, pr[2*g+1].z}, (v2f){w2, w2}, p1v[g]);
                p1v[g] = fma2((v2f){pr[2*g].w, pr[2*g+1].w}, (v2f){w3, w3}, p1v[g]);
            }
        }
        float fhv[TPW];
        #pragma unroll
        for (int t = 0; t < TPW; ++t) {
            float p1 = (t & 1) ? p1v[t >> 1].y : p1v[t >> 1].x;
            fhv[t] = eluf(p1 + __shfl_xor(p1, 32));
        }

        float p2[TPW];
        float f2b = ldf<BF16>(fl2b, jj);
        #pragma unroll
        for (int t = 0; t < TPW; ++t) p2[t] = f2b;
        #pragma unroll
        for (int k = 0; k < 32; ++k) {
            float wv = ldf<BF16>(fl2w, k * 32 + jj);
            #pragma unroll
            for (int t = 0; t < TPW; ++t) p2[t] += rlane(fhv[t], k) * wv;
        }
        float p3[TPW];
        float fgbv = ldf<BF16>(flgb, lane);
        #pragma unroll
        for (int t = 0; t < TPW; ++t) p3[t] = fgbv;
        #pragma unroll
        for (int k = 0; k < 32; ++k) {
            float wv = ldf<BF16>(flgw, k * 64 + lane);
            #pragma unroll
            for (int t = 0; t < TPW; ++t) p3[t] += rlane(p2[t], k) * wv;
        }

        float lng = ldf<BF16>(flng, jj), lnb = ldf<BF16>(flnb, jj);
        float posB = (float)jj * (255.0f / 31.0f);
        int loB = (int)floorf(posB); loB = loB < 0 ? 0 : (loB > 254 ? 254 : loB);
        float frB = posB - (float)loB;

        #pragma unroll
        for (int t = 0; t < TPW; ++t) {
            float fgA  = __shfl(p3[t], jj);
            float fgB  = __shfl(p3[t], jj + 32);
            float fglu = fgA * sigm(fgB);
            float pl = preS[t * 256 + loB];
            float ph = preS[t * 256 + loB + 1];
            float tv = fglu + pl + frB * (ph - pl);
            float S1 = rsum32(tv);
            float S2 = rsum32(tv * tv);
            float mean = S1 * (1.0f / 32.0f);
            float var  = fmaxf(S2 * (1.0f / 32.0f) - mean * mean, 0.0f);
            float rs   = rsqf_(var + 1e-5f);
            float wl   = (tv - mean) * rs * lng + lnb;
            float mx   = rmax32(wl);
            float e    = __expf(wl - mx);
            float ss   = rsum32(e);
            float wv   = e * rcpf_(ss);
            wreg[t] = wv;
            if (wave == 0 && lane < 32) stf<BF16>(outW, (size_t)(tokBase + t) * NF + lane, wv);
        }
    }

    float acc[TPW][5];
    #pragma unroll
    for (int t = 0; t < TPW; ++t)
        #pragma unroll
        for (int i = 0; i < 5; ++i) acc[t][i] = 0.0f;

    // ---- feature loop (f-split): this wave's 16 features, all 8 tokens ----
    for (int fi = 0; fi < NF / WPB; ++fi) {
        const int f = fBase + fi;
        // load this f's 5 packed rows for this lane's d values
        v2f  P[5][8];
        float bcA[5], bcB[5], lgv[5], lbv[5], rwv[5], rbv[5];
        #pragma unroll
        for (int i = 0; i < 5; ++i) {
            int d = i * 64 + lane;
            int dcl = d < ND ? d : ND - 1;
            const unsigned* rp = Crow + ((size_t)f * ND + dcl) * 16;
            uint4 c0 = *(const uint4*)(rp + 0);
            uint4 c1 = *(const uint4*)(rp + 4);
            uint4 c2 = *(const uint4*)(rp + 8);
            uint2 c3 = *(const uint2*)(rp + 12);
            P[i][0] = unpk(c0.x); P[i][1] = unpk(c0.y);
            P[i][2] = unpk(c0.z); P[i][3] = unpk(c0.w);
            P[i][4] = unpk(c1.x); P[i][5] = unpk(c1.y);
            P[i][6] = unpk(c1.z); P[i][7] = unpk(c1.w);
            bcA[i] = __uint_as_float(c2.x);
            bcB[i] = __uint_as_float(c2.y);
            lgv[i] = __uint_as_float(c2.z);
            lbv[i] = __uint_as_float(c2.w);
            rwv[i] = __uint_as_float(c3.x);
            rbv[i] = __uint_as_float(c3.y);
        }

        float xq = (fi < 8) ? xrA : xrB;    // wave-uniform select

        #pragma unroll
        for (int t = 0; t < TPW; ++t) {
            uint4 hp = *(const uint4*)(&hS[t * 128 + f * 4]);   // 8 bf16 h values
            v2f h01 = unpk(hp.x), h23 = unpk(hp.y), h45 = unpk(hp.z), h67 = unpk(hp.w);
            float xv = rlane(xq, ((fi & 7) << 3) | t);           // x[tok t, feature f]

            float tt[5], a1 = 0.f, a2 = 0.f;
            #pragma unroll
            for (int i = 0; i < 5; ++i) {
                int d = i * 64 + lane;
                bool ok = (d < ND);
                v2f g = {bcA[i], bcB[i]};             // {gA, gB*log2e}
                g = fma2s(h01.x, P[i][0], g);
                g = fma2s(h01.y, P[i][1], g);
                g = fma2s(h23.x, P[i][2], g);
                g = fma2s(h23.y, P[i][3], g);
                g = fma2s(h45.x, P[i][4], g);
                g = fma2s(h45.y, P[i][5], g);
                g = fma2s(h67.x, P[i][6], g);
                g = fma2s(h67.y, P[i][7], g);
                float tv = fmaf(xv, rwv[i], rbv[i]) + g.x * sigm2(g.y);  // glu + residual
                tv = ok ? tv : 0.0f;
                tt[i] = tv; a1 += tv; a2 = fmaf(tv, tv, a2);
            }

            float S1 = wsum64(a1);
            float S2 = wsum64(a2);
            float mean = S1 * (1.0f / 300.0f);
            float var  = fmaxf(S2 * (1.0f / 300.0f) - mean * mean, 0.0f);
            float rs   = rsqf_(var + 1e-5f);
            float wf   = rlane(wreg[t], f);            // dynamic-uniform readlane
            float c1v  = wf * rs;
            float c2v  = -c1v * mean;
            // acc += wf*((tt-mean)*rs*lg + lb)  ==  fma(lg, fma(c1,tt,c2), fma(wf,lb,acc))
            #pragma unroll
            for (int i = 0; i < 5; ++i) {
                int d = i * 64 + lane;
                if (d < ND) {
                    float v = fmaf(c1v, tt[i], c2v);
                    acc[t][i] = fmaf(lgv[i], v, fmaf(wf, lbv[i], acc[t][i]));
                }
            }
        }
    }

    // ---- acc merge via LDS (preS dead after Stage B) + write out ----
    __syncthreads();   // all feature-loop work (and Stage-B preS reads) done
    if (wave == 0) {
        #pragma unroll
        for (int t = 0; t < TPW; ++t)
            #pragma unroll
            for (int i = 0; i < 5; ++i)
                preS[(t * 5 + i) * 64 + lane] = acc[t][i];
    }
    __syncthreads();
    if (wave == 1) {
        #pragma unroll
        for (int t = 0; t < TPW; ++t) {
            const size_t tok = (size_t)tokBase + t;
            #pragma unroll
            for (int i = 0; i < 5; ++i) {
                int d = i * 64 + lane;
                if (d < ND)
                    stf<BF16>(outMain, tok * ND + d, acc[t][i] + preS[(t * 5 + i) * 64 + lane]);
            }
        }
    }
}

__launch_bounds__(128)
__global__ void vsn_main(const void* __restrict__ x,
                         const void* __restrict__ pre_w, const void* __restrict__ pre_b,
                         const void* __restrict__ W1,    const void* __restrict__ b1,
                         const void* __restrict__ fl1w,  const void* __restrict__ fl1b,
                         const void* __restrict__ fl2w,  const void* __restrict__ fl2b,
                         const void* __restrict__ flgw,  const void* __restrict__ flgb,
                         const void* __restrict__ flng,  const void* __restrict__ flnb,
                         const unsigned* __restrict__ Crow, void* __restrict__ d_out)
{
    __shared__ float    preS_[2560];   // [8 tok][256] staging (2048) / acc-merge (2560) — 10 KB
    __shared__ unsigned hS_[TPB * 128];  // 4 KB bf16-packed h
    if (is_bf16(flng))   // fl_ln_g is ones
        vsn_body<1>(x, pre_w, pre_b, W1, b1, fl1w, fl1b, fl2w, fl2b,
                    flgw, flgb, flng, flnb, Crow, d_out, preS_, hS_);
    else
        vsn_body<0>(x, pre_w, pre_b, W1, b1, fl1w, fl1b, fl2w, fl2b,
                    flgw, flgb, flng, flnb, Crow, d_out, preS_, hS_);
}

extern "C" void kernel_launch(void* const* d_in, const int* in_sizes, int n_in,
                              void* d_out, int out_size, void* d_ws, size_t ws_size,
                              hipStream_t stream)
{
    const void* x     = d_in[0];
    const void* pre_w = d_in[1];
    const void* pre_b = d_in[2];
    const void* W1    = d_in[3];
    const void* b1    = d_in[4];
    const void* W2    = d_in[5];
    const void* b2    = d_in[6];
    const void* Wg    = d_in[7];
    const void* bg    = d_in[8];
    const void* sg_g  = d_in[9];
    const void* sg_b  = d_in[10];
    const void* fl1w  = d_in[11];
    const void* fl1b  = d_in[12];
    const void* fl2w  = d_in[13];
    const void* fl2b  = d_in[14];
    const void* flgw  = d_in[15];
    const void* flgb  = d_in[16];
    const void* flng  = d_in[17];
    const void* flnb  = d_in[18];

    unsigned* Crow = (unsigned*)d_ws;    // 9600 rows x 64 B = 600 KB

    precompute_kernel<<<160, 512, 0, stream>>>(W2, b2, Wg, bg, sg_g, sg_b,
                                               pre_w, pre_b, Crow);

    vsn_main<<<NTOK / TPB, 128, 0, stream>>>(x, pre_w, pre_b, W1, b1,
        fl1w, fl1b, fl2w, fl2b, flgw, flgb, flng, flnb, Crow, d_out);
}

// Round 4
// 298.840 us; speedup vs baseline: 1.1521x; 1.1521x over previous
//
#include <hip/hip_runtime.h>
#include <hip/hip_bf16.h>

// Problem constants (B=32, S=512, F=32, H=8, D=300, FH=32)
#define NB 32
#define NS 512
#define NF 32
#define NH 8
#define ND 300
#define NTOK (NB*NS)      // 16384 tokens
#define TPW 8             // tokens per wave (R13: R2 frame restored — wave-split (R3)
                          // conserved VALU time but added barrier/merge stalls)
#define WPB 2             // waves per block; wave-private LDS, zero barriers
#define TPB (TPW*WPB)     // 16 tokens per block -> grid 1024

#define L2E 1.4426950408889634f

using bf16 = __hip_bfloat16;
typedef float v2f __attribute__((ext_vector_type(2)));

__device__ __forceinline__ float rcpf_(float x){ return __builtin_amdgcn_rcpf(x); }
__device__ __forceinline__ float rsqf_(float x){ return __builtin_amdgcn_rsqf(x); }
__device__ __forceinline__ float sigm(float x){ return rcpf_(1.0f + __expf(-x)); }
// gate-B coefficients are pre-scaled by log2(e) in precompute -> exp2 directly
__device__ __forceinline__ float sigm2(float x){ return rcpf_(1.0f + __builtin_amdgcn_exp2f(-x)); }
__device__ __forceinline__ float eluf(float x){ return x > 0.0f ? x : __expf(x) - 1.0f; }

// packed fp32 FMA -> v_pk_fma_f32
__device__ __forceinline__ v2f fma2(v2f a, v2f b, v2f c){
    return __builtin_elementwise_fma(a, b, c);
}
__device__ __forceinline__ v2f fma2s(float s, v2f b, v2f c){
    return __builtin_elementwise_fma((v2f){s, s}, b, c);
}

template<int BF16>
__device__ __forceinline__ float ldf(const void* p, size_t i){
    if (BF16) return __bfloat162float(((const bf16*)p)[i]);
    return ((const float*)p)[i];
}
template<int BF16>
__device__ __forceinline__ void stf(void* p, size_t i, float v){
    if (BF16) ((bf16*)p)[i] = __float2bfloat16(v);
    else      ((float*)p)[i] = v;
}

// dtype test on a known-ones tensor: bf16 pair -> 0x3F803F80, fp32 -> 0x3F800000
__device__ __forceinline__ bool is_bf16(const void* ones){
    return *(const unsigned*)ones == 0x3F803F80u;
}

// bf16 pair (lo,hi) -> v2f {lo,hi}: 2 VALU ops
__device__ __forceinline__ v2f unpk(unsigned u){
    return (v2f){ __int_as_float((int)(u << 16)),
                  __int_as_float((int)(u & 0xFFFF0000u)) };
}
__device__ __forceinline__ unsigned pack_bf(float a, float b){
    bf16 ha = __float2bfloat16(a), hb = __float2bfloat16(b);
    return (unsigned)*(unsigned short*)&ha | ((unsigned)*(unsigned short*)&hb << 16);
}

// ---------------- DPP reductions (VALU pipe — keeps the LDS pipe free) ------
template<int CTRL>
__device__ __forceinline__ float dppadd(float v){
    return v + __int_as_float(__builtin_amdgcn_update_dpp(
        0, __float_as_int(v), CTRL, 0xF, 0xF, true));
}
template<int CTRL>
__device__ __forceinline__ float dppmax(float v){
    return fmaxf(v, __int_as_float(__builtin_amdgcn_update_dpp(
        __float_as_int(v), __float_as_int(v), CTRL, 0xF, 0xF, false)));
}
__device__ __forceinline__ float rlane(float v, int l){
    return __int_as_float(__builtin_amdgcn_readlane(__float_as_int(v), l));
}
__device__ __forceinline__ float wsum64(float v){
    v = dppadd<0x111>(v); v = dppadd<0x112>(v); v = dppadd<0x114>(v); v = dppadd<0x118>(v);
    v = dppadd<0x142>(v); v = dppadd<0x143>(v);
    return rlane(v, 63);
}
__device__ __forceinline__ float rsum32(float v){
    v = dppadd<0x111>(v); v = dppadd<0x112>(v); v = dppadd<0x114>(v); v = dppadd<0x118>(v);
    return rlane(v, 15) + rlane(v, 31);
}
__device__ __forceinline__ float rmax32(float v){
    v = dppmax<0x111>(v); v = dppmax<0x112>(v); v = dppmax<0x114>(v); v = dppmax<0x118>(v);
    return fmaxf(rlane(v, 15), rlane(v, 31));
}

// ---------------------------------------------------------------------------
// Precompute packed rows of 16 dwords (= one 64B line) per (f,d):
//   dword 0..7 : bf16 pair (lo=A_k, hi=B_k*log2e), k=0..7   [gate coeffs, folded fc2]
//   dword 8    : bcA (fp32)   dword 9: bcB*log2e (fp32)
//   dword 10,11: sg_ln_g, sg_ln_b (fp32)
//   dword 12,13: rw, rb (fp32)  [residual folded: interp(pre)=x*rw+rb —
//                kills 10 LDS reads + addr math per (f,t) in the hot i-loop]
//   dword 14,15: pad
// ---------------------------------------------------------------------------
template<int BF16>
__device__ void precompute_body(const void* __restrict__ W2, const void* __restrict__ b2,
                                const void* __restrict__ Wg, const void* __restrict__ bg,
                                const void* __restrict__ sg_g, const void* __restrict__ sg_b,
                                const void* __restrict__ pre_w, const void* __restrict__ pre_b,
                                unsigned* __restrict__ Crow,
                                float* __restrict__ w2t, float* __restrict__ b2s,
                                float (*part)[64][18])
{
    const int tid  = threadIdx.x;
    const int lane = tid & 63;
    const int wv   = tid >> 6;            // 0..7: m-chunk
    const int f    = blockIdx.x & 31;     // 160 blocks = 32 f x 5 d-chunks
    const int c    = blockIdx.x >> 5;     // 0..4
    const int d    = c * 64 + lane;       // 0..319 (chunk 4 partially masked)
    const int dc   = d < 299 ? d : 299;   // clamp for loads (keeps Wg in-bounds)

    // stage W2 transposed [m][k] (fp32) + b2 for this f
    for (int idx = tid; idx < 2400; idx += 512) {
        int m = idx >> 3, k = idx & 7;
        w2t[idx] = ldf<BF16>(W2, (size_t)f * 2400 + (size_t)k * 300 + m);
    }
    if (tid < 300) b2s[tid] = ldf<BF16>(b2, (size_t)f * 300 + tid);
    __syncthreads();

    v2f aA01 = {0,0}, aA23 = {0,0}, aA45 = {0,0}, aA67 = {0,0};
    v2f aB01 = {0,0}, aB23 = {0,0}, aB45 = {0,0}, aB67 = {0,0};
    float bAa = 0.f, bBa = 0.f;

    const int m0 = (wv * 300) >> 3;
    const int m1 = ((wv + 1) * 300) >> 3;
    const size_t WgF = (size_t)f * 180000 + dc;
    #pragma unroll 4
    for (int m = m0; m < m1; ++m) {
        float wa = ldf<BF16>(Wg, WgF + (size_t)m * 600);        // coalesced across lanes
        float wb = ldf<BF16>(Wg, WgF + (size_t)m * 600 + 300);  // coalesced across lanes
        float4 wk0 = *(const float4*)(w2t + m * 8);             // k0..3 (broadcast)
        float4 wk1 = *(const float4*)(w2t + m * 8 + 4);         // k4..7 (broadcast)
        aA01 = fma2s(wa, (v2f){wk0.x, wk0.y}, aA01);
        aA23 = fma2s(wa, (v2f){wk0.z, wk0.w}, aA23);
        aA45 = fma2s(wa, (v2f){wk1.x, wk1.y}, aA45);
        aA67 = fma2s(wa, (v2f){wk1.z, wk1.w}, aA67);
        aB01 = fma2s(wb, (v2f){wk0.x, wk0.y}, aB01);
        aB23 = fma2s(wb, (v2f){wk0.z, wk0.w}, aB23);
        aB45 = fma2s(wb, (v2f){wk1.x, wk1.y}, aB45);
        aB67 = fma2s(wb, (v2f){wk1.z, wk1.w}, aB67);
        float b2v = b2s[m];
        bAa += b2v * wa;
        bBa += b2v * wb;
    }

    {
        float* p = part[wv][lane];
        p[0]  = aA01.x; p[1]  = aA01.y; p[2]  = aA23.x; p[3]  = aA23.y;
        p[4]  = aA45.x; p[5]  = aA45.y; p[6]  = aA67.x; p[7]  = aA67.y;
        p[8]  = aB01.x; p[9]  = aB01.y; p[10] = aB23.x; p[11] = aB23.y;
        p[12] = aB45.x; p[13] = aB45.y; p[14] = aB67.x; p[15] = aB67.y;
        p[16] = bAa;    p[17] = bBa;
    }
    __syncthreads();

    if (tid < 64 && d < 300) {
        float s[18];
        #pragma unroll
        for (int v = 0; v < 18; ++v) {
            float t0 = part[0][lane][v] + part[1][lane][v];
            float t1 = part[2][lane][v] + part[3][lane][v];
            float t2 = part[4][lane][v] + part[5][lane][v];
            float t3 = part[6][lane][v] + part[7][lane][v];
            s[v] = (t0 + t1) + (t2 + t3);
        }
        unsigned dw[12];
        #pragma unroll
        for (int k = 0; k < 8; ++k) dw[k] = pack_bf(s[k], s[8 + k] * L2E);
        dw[8]  = __float_as_uint(s[16] + ldf<BF16>(bg, (size_t)f * 600 + d));
        dw[9]  = __float_as_uint((s[17] + ldf<BF16>(bg, (size_t)f * 600 + d + 300)) * L2E);
        dw[10] = __float_as_uint(ldf<BF16>(sg_g, (size_t)f * 300 + d));
        dw[11] = __float_as_uint(ldf<BF16>(sg_b, (size_t)f * 300 + d));

        // residual fold: rw = interp(pre_w[f,:]) at d, rb = interp(pre_b[f,:])
        float pos = (float)d * (7.0f / 299.0f);
        int lo = (int)floorf(pos); lo = lo < 0 ? 0 : (lo > 6 ? 6 : lo);
        float fr = pos - (float)lo;
        float pwl = ldf<BF16>(pre_w, (size_t)f * 8 + lo);
        float pwh = ldf<BF16>(pre_w, (size_t)f * 8 + lo + 1);
        float pbl = ldf<BF16>(pre_b, (size_t)f * 8 + lo);
        float pbh = ldf<BF16>(pre_b, (size_t)f * 8 + lo + 1);
        unsigned rwu = __float_as_uint(pwl + fr * (pwh - pwl));
        unsigned rbu = __float_as_uint(pbl + fr * (pbh - pbl));

        unsigned* row = Crow + (size_t)(f * 300 + d) * 16;
        *(uint4*)(row + 0)  = make_uint4(dw[0], dw[1], dw[2],  dw[3]);
        *(uint4*)(row + 4)  = make_uint4(dw[4], dw[5], dw[6],  dw[7]);
        *(uint4*)(row + 8)  = make_uint4(dw[8], dw[9], dw[10], dw[11]);
        *(uint4*)(row + 12) = make_uint4(rwu, rbu, 0u, 0u);
    }
}

__global__ void precompute_kernel(const void* __restrict__ W2, const void* __restrict__ b2,
                                  const void* __restrict__ Wg, const void* __restrict__ bg,
                                  const void* __restrict__ sg_g, const void* __restrict__ sg_b,
                                  const void* __restrict__ pre_w, const void* __restrict__ pre_b,
                                  unsigned* __restrict__ Crow)
{
    __shared__ float w2t[2400];          // W2 transposed [m][k], fp32
    __shared__ float b2s[300];
    __shared__ float part[8][64][18];    // per-wave partials
    if (is_bf16(sg_g))   // sg_ln_g is ones
        precompute_body<1>(W2, b2, Wg, bg, sg_g, sg_b, pre_w, pre_b, Crow, w2t, b2s, part);
    else
        precompute_body<0>(W2, b2, Wg, bg, sg_g, sg_b, pre_w, pre_b, Crow, w2t, b2s, part);
}

// ---------------------------------------------------------------------------
// Main kernel (R13): R2 frame — 16 tokens/block (2 waves x 8 tokens), zero
// barriers, wave-private LDS (24 KB/block). Hot-loop cuts vs R2:
//   * per-feature residual folded to x*rw+rb (rw/rb from Crow): removes
//     10 ds_read + interp/addr VALU per (f,t); x held in 4 regs, readlane'd
//   * i=4 specialization: lane-mask (d>=300) only where it can occur;
//     i=0..3 run unguarded (d<=255 always valid)
// R3 lesson: wave count is NOT the lever (VALU-busy time conserved at 155us);
// instruction count is.
// ---------------------------------------------------------------------------
template<int BF16>
__device__ void vsn_body(const void* __restrict__ x,
                         const void* __restrict__ pre_w, const void* __restrict__ pre_b,
                         const void* __restrict__ W1,    const void* __restrict__ b1,
                         const void* __restrict__ fl1w,  const void* __restrict__ fl1b,
                         const void* __restrict__ fl2w,  const void* __restrict__ fl2b,
                         const void* __restrict__ flgw,  const void* __restrict__ flgb,
                         const void* __restrict__ flng,  const void* __restrict__ flnb,
                         const unsigned* __restrict__ Crow,
                         void* __restrict__ d_out, float* preS_, unsigned* hS_)
{
    void* outMain = d_out;                                             // [B,S,D]
    void* outW    = (char*)d_out + (size_t)NTOK * ND * (BF16 ? 2 : 4); // [B,S,1,F]

    const int tid  = threadIdx.x;
    const int wave = tid >> 6;
    const int lane = tid & 63;
    const int tokBase = blockIdx.x * TPB + wave * TPW;   // this wave's 8 tokens

    float*    myPre = preS_ + wave * (TPW * 256);
    unsigned* myH   = hS_   + wave * (TPW * 128);        // 128 dwords (256 bf16)/token

    // ---- x in registers: xr_q holds x[tok = lane&7, f = q*8 + (lane>>3)] ----
    float xr0, xr1, xr2, xr3;
    {
        const int tx = lane & 7, fo = lane >> 3;
        const size_t bx = (size_t)(tokBase + tx) * NF + fo;
        xr0 = ldf<BF16>(x, bx);
        xr1 = ldf<BF16>(x, bx + 8);
        xr2 = ldf<BF16>(x, bx + 16);
        xr3 = ldf<BF16>(x, bx + 24);
    }

    // ---- Stage A: pre = x*pre_w + pre_b ----
    {
        float pw[4], pb[4];
        #pragma unroll
        for (int q = 0; q < 4; ++q) {
            pw[q] = ldf<BF16>(pre_w, 4 * lane + q);
            pb[q] = ldf<BF16>(pre_b, 4 * lane + q);
        }
        const int fidx = lane >> 1;
        #pragma unroll
        for (int t = 0; t < TPW; ++t) {
            float xv = ldf<BF16>(x, (size_t)(tokBase + t) * NF + fidx);
            float4 v;
            v.x = xv * pw[0] + pb[0];
            v.y = xv * pw[1] + pb[1];
            v.z = xv * pw[2] + pb[2];
            v.w = xv * pw[3] + pb[3];
            *(float4*)(&myPre[t * 256 + 4 * lane]) = v;
        }
    }

    // ---- Stage H: h = elu(pre @ W1 + b1), stored bf16-packed ----
    {
        const int f  = lane >> 1;
        const int kh = (lane & 1) * 4;
        float w1r[8][4], b1r[4];
        #pragma unroll
        for (int m = 0; m < 8; ++m)
            #pragma unroll
            for (int q = 0; q < 4; ++q)
                w1r[m][q] = ldf<BF16>(W1, (size_t)(f * 8 + m) * 8 + kh + q);
        #pragma unroll
        for (int q = 0; q < 4; ++q) b1r[q] = ldf<BF16>(b1, f * 8 + kh + q);

        #pragma unroll
        for (int t = 0; t < TPW; ++t) {
            float pr[8];
            float4 pA = *(const float4*)(&myPre[t * 256 + f * 8]);
            float4 pB = *(const float4*)(&myPre[t * 256 + f * 8 + 4]);
            pr[0]=pA.x; pr[1]=pA.y; pr[2]=pA.z; pr[3]=pA.w;
            pr[4]=pB.x; pr[5]=pB.y; pr[6]=pB.z; pr[7]=pB.w;
            float a[4] = {b1r[0], b1r[1], b1r[2], b1r[3]};
            #pragma unroll
            for (int m = 0; m < 8; ++m)
                #pragma unroll
                for (int q = 0; q < 4; ++q)
                    a[q] += pr[m] * w1r[m][q];
            uint2 hp;
            hp.x = pack_bf(eluf(a[0]), eluf(a[1]));
            hp.y = pack_bf(eluf(a[2]), eluf(a[3]));
            *(uint2*)(&myH[t * 128 + 2 * lane]) = hp;    // dwords 2l,2l+1 = cols 4l..4l+3
        }
    }

    // ---- Stage B: flattened GRN -> softmax weights (8 tokens/wave) ----
    const int jj = lane & 31;
    const int hB = lane >> 5;
    float wreg[TPW];
    {
        float f1b = (hB == 0) ? ldf<BF16>(fl1b, jj) : 0.0f;
        v2f p1v[TPW / 2];
        #pragma unroll
        for (int g = 0; g < TPW / 2; ++g) p1v[g] = (v2f){f1b, f1b};
        for (int kg = 0; kg < 32; ++kg) {
            const int kk = hB * 128 + kg * 4;
            float4 pr[TPW];
            #pragma unroll
            for (int t = 0; t < TPW; ++t)
                pr[t] = *(const float4*)(&myPre[t * 256 + kk]);
            float w0 = ldf<BF16>(fl1w, (size_t)(kk + 0) * 32 + jj);
            float w1 = ldf<BF16>(fl1w, (size_t)(kk + 1) * 32 + jj);
            float w2 = ldf<BF16>(fl1w, (size_t)(kk + 2) * 32 + jj);
            float w3 = ldf<BF16>(fl1w, (size_t)(kk + 3) * 32 + jj);
            #pragma unroll
            for (int g = 0; g < TPW / 2; ++g) {
                p1v[g] = fma2((v2f){pr[2*g].x, pr[2*g+1].x}, (v2f){w0, w0}, p1v[g]);
                p1v[g] = fma2((v2f){pr[2*g].y, pr[2*g+1].y}, (v2f){w1, w1}, p1v[g]);
                p1v[g] = fma2((v2f){pr[2*g].z, pr[2*g+1].z}, (v2f){w2, w2}, p1v[g]);
                p1v[g] = fma2((v2f){pr[2*g].w, pr[2*g+1].w}, (v2f){w3, w3}, p1v[g]);
            }
        }
        float fhv[TPW];
        #pragma unroll
        for (int t = 0; t < TPW; ++t) {
            float p1 = (t & 1) ? p1v[t >> 1].y : p1v[t >> 1].x;
            fhv[t] = eluf(p1 + __shfl_xor(p1, 32));
        }

        float p2[TPW];
        float f2b = ldf<BF16>(fl2b, jj);
        #pragma unroll
        for (int t = 0; t < TPW; ++t) p2[t] = f2b;
        #pragma unroll
        for (int k = 0; k < 32; ++k) {
            float wv = ldf<BF16>(fl2w, k * 32 + jj);
            #pragma unroll
            for (int t = 0; t < TPW; ++t) p2[t] += rlane(fhv[t], k) * wv;
        }
        float p3[TPW];
        float fgbv = ldf<BF16>(flgb, lane);
        #pragma unroll
        for (int t = 0; t < TPW; ++t) p3[t] = fgbv;
        #pragma unroll
        for (int k = 0; k < 32; ++k) {
            float wv = ldf<BF16>(flgw, k * 64 + lane);
            #pragma unroll
            for (int t = 0; t < TPW; ++t) p3[t] += rlane(p2[t], k) * wv;
        }

        float lng = ldf<BF16>(flng, jj), lnb = ldf<BF16>(flnb, jj);
        float posB = (float)jj * (255.0f / 31.0f);
        int loB = (int)floorf(posB); loB = loB < 0 ? 0 : (loB > 254 ? 254 : loB);
        float frB = posB - (float)loB;

        #pragma unroll
        for (int t = 0; t < TPW; ++t) {
            float fgA  = __shfl(p3[t], jj);
            float fgB  = __shfl(p3[t], jj + 32);
            float fglu = fgA * sigm(fgB);
            float pl = myPre[t * 256 + loB];
            float ph = myPre[t * 256 + loB + 1];
            float tv = fglu + pl + frB * (ph - pl);
            float S1 = rsum32(tv);
            float S2 = rsum32(tv * tv);
            float mean = S1 * (1.0f / 32.0f);
            float var  = fmaxf(S2 * (1.0f / 32.0f) - mean * mean, 0.0f);
            float rs   = rsqf_(var + 1e-5f);
            float wl   = (tv - mean) * rs * lng + lnb;
            float mx   = rmax32(wl);
            float e    = __expf(wl - mx);
            float ss   = rsum32(e);
            float wv   = e * rcpf_(ss);
            wreg[t] = wv;
            if (lane < 32) stf<BF16>(outW, (size_t)(tokBase + t) * NF + lane, wv);
        }
    }

    float acc[TPW][5];
    #pragma unroll
    for (int t = 0; t < TPW; ++t)
        #pragma unroll
        for (int i = 0; i < 5; ++i) acc[t][i] = 0.0f;

    // ---- feature loop: packed C rows from global (L2), t-outer epilogue ----
    for (int f = 0; f < NF; ++f) {
        // load this f's 5 packed rows for this lane's d values
        v2f  P[5][8];
        float bcA[5], bcB[5], lgv[5], lbv[5], rwv[5], rbv[5];
        #pragma unroll
        for (int i = 0; i < 5; ++i) {
            int d = i * 64 + lane;
            int dcl = d < ND ? d : ND - 1;
            const unsigned* rp = Crow + ((size_t)f * ND + dcl) * 16;
            uint4 c0 = *(const uint4*)(rp + 0);
            uint4 c1 = *(const uint4*)(rp + 4);
            uint4 c2 = *(const uint4*)(rp + 8);
            uint2 c3 = *(const uint2*)(rp + 12);
            P[i][0] = unpk(c0.x); P[i][1] = unpk(c0.y);
            P[i][2] = unpk(c0.z); P[i][3] = unpk(c0.w);
            P[i][4] = unpk(c1.x); P[i][5] = unpk(c1.y);
            P[i][6] = unpk(c1.z); P[i][7] = unpk(c1.w);
            bcA[i] = __uint_as_float(c2.x);
            bcB[i] = __uint_as_float(c2.y);
            lgv[i] = __uint_as_float(c2.z);
            lbv[i] = __uint_as_float(c2.w);
            rwv[i] = __uint_as_float(c3.x);
            rbv[i] = __uint_as_float(c3.y);
        }

        float xq = (f < 8) ? xr0 : (f < 16) ? xr1 : (f < 24) ? xr2 : xr3;
        const int fl3 = (f & 7) << 3;

        #pragma unroll
        for (int t = 0; t < TPW; ++t) {
            uint4 hp = *(const uint4*)(&myH[t * 128 + f * 4]);   // 8 bf16 h values
            v2f h01 = unpk(hp.x), h23 = unpk(hp.y), h45 = unpk(hp.z), h67 = unpk(hp.w);
            float xv = rlane(xq, fl3 | t);                       // x[tok t, feature f]

            float tt[5], a1 = 0.f, a2 = 0.f;
            #pragma unroll
            for (int i = 0; i < 4; ++i) {          // d = i*64+lane <= 255: always valid
                v2f g = {bcA[i], bcB[i]};             // {gA, gB*log2e}
                g = fma2s(h01.x, P[i][0], g);
                g = fma2s(h01.y, P[i][1], g);
                g = fma2s(h23.x, P[i][2], g);
                g = fma2s(h23.y, P[i][3], g);
                g = fma2s(h45.x, P[i][4], g);
                g = fma2s(h45.y, P[i][5], g);
                g = fma2s(h67.x, P[i][6], g);
                g = fma2s(h67.y, P[i][7], g);
                float tv = fmaf(xv, rwv[i], rbv[i]) + g.x * sigm2(g.y);  // glu + residual
                tt[i] = tv; a1 += tv; a2 = fmaf(tv, tv, a2);
            }
            {                                       // i = 4: d = 256+lane, valid iff lane < 44
                v2f g = {bcA[4], bcB[4]};
                g = fma2s(h01.x, P[4][0], g);
                g = fma2s(h01.y, P[4][1], g);
                g = fma2s(h23.x, P[4][2], g);
                g = fma2s(h23.y, P[4][3], g);
                g = fma2s(h45.x, P[4][4], g);
                g = fma2s(h45.y, P[4][5], g);
                g = fma2s(h67.x, P[4][6], g);
                g = fma2s(h67.y, P[4][7], g);
                float tv = fmaf(xv, rwv[4], rbv[4]) + g.x * sigm2(g.y);
                tv = (lane < (ND - 256)) ? tv : 0.0f;
                tt[4] = tv; a1 += tv; a2 = fmaf(tv, tv, a2);
            }

            float S1 = wsum64(a1);
            float S2 = wsum64(a2);
            float mean = S1 * (1.0f / 300.0f);
            float var  = fmaxf(S2 * (1.0f / 300.0f) - mean * mean, 0.0f);
            float rs   = rsqf_(var + 1e-5f);
            float wf   = rlane(wreg[t], f);            // dynamic-uniform readlane
            float c1v  = wf * rs;
            float c2v  = -c1v * mean;
            // acc += wf*((tt-mean)*rs*lg + lb)  ==  fma(lg, fma(c1,tt,c2), fma(wf,lb,acc))
            #pragma unroll
            for (int i = 0; i < 4; ++i)
                acc[t][i] = fmaf(lgv[i], fmaf(c1v, tt[i], c2v), fmaf(wf, lbv[i], acc[t][i]));
            if (lane < (ND - 256))
                acc[t][4] = fmaf(lgv[4], fmaf(c1v, tt[4], c2v), fmaf(wf, lbv[4], acc[t][4]));
        }
    }

    // ---- write out ----
    #pragma unroll
    for (int t = 0; t < TPW; ++t) {
        const size_t tok = (size_t)tokBase + t;
        #pragma unroll
        for (int i = 0; i < 4; ++i)
            stf<BF16>(outMain, tok * ND + i * 64 + lane, acc[t][i]);
        if (lane < (ND - 256))
            stf<BF16>(outMain, tok * ND + 256 + lane, acc[t][4]);
    }
}

__launch_bounds__(128)
__global__ void vsn_main(const void* __restrict__ x,
                         const void* __restrict__ pre_w, const void* __restrict__ pre_b,
                         const void* __restrict__ W1,    const void* __restrict__ b1,
                         const void* __restrict__ fl1w,  const void* __restrict__ fl1b,
                         const void* __restrict__ fl2w,  const void* __restrict__ fl2b,
                         const void* __restrict__ flgw,  const void* __restrict__ flgb,
                         const void* __restrict__ flng,  const void* __restrict__ flnb,
                         const unsigned* __restrict__ Crow, void* __restrict__ d_out)
{
    __shared__ float    preS_[WPB * TPW * 256];   // 16 KB fp32
    __shared__ unsigned hS_[WPB * TPW * 128];     // 8 KB bf16-packed
    if (is_bf16(flng))   // fl_ln_g is ones
        vsn_body<1>(x, pre_w, pre_b, W1, b1, fl1w, fl1b, fl2w, fl2b,
                    flgw, flgb, flng, flnb, Crow, d_out, preS_, hS_);
    else
        vsn_body<0>(x, pre_w, pre_b, W1, b1, fl1w, fl1b, fl2w, fl2b,
                    flgw, flgb, flng, flnb, Crow, d_out, preS_, hS_);
}

extern "C" void kernel_launch(void* const* d_in, const int* in_sizes, int n_in,
                              void* d_out, int out_size, void* d_ws, size_t ws_size,
                              hipStream_t stream)
{
    const void* x     = d_in[0];
    const void* pre_w = d_in[1];
    const void* pre_b = d_in[2];
    const void* W1    = d_in[3];
    const void* b1    = d_in[4];
    const void* W2    = d_in[5];
    const void* b2    = d_in[6];
    const void* Wg    = d_in[7];
    const void* bg    = d_in[8];
    const void* sg_g  = d_in[9];
    const void* sg_b  = d_in[10];
    const void* fl1w  = d_in[11];
    const void* fl1b  = d_in[12];
    const void* fl2w  = d_in[13];
    const void* fl2b  = d_in[14];
    const void* flgw  = d_in[15];
    const void* flgb  = d_in[16];
    const void* flng  = d_in[17];
    const void* flnb  = d_in[18];

    unsigned* Crow = (unsigned*)d_ws;    // 9600 rows x 64 B = 600 KB

    precompute_kernel<<<160, 512, 0, stream>>>(W2, b2, Wg, bg, sg_g, sg_b,
                                               pre_w, pre_b, Crow);

    vsn_main<<<NTOK / TPB, 128, 0, stream>>>(x, pre_w, pre_b, W1, b1,
        fl1w, fl1b, fl2w, fl2b, flgw, flgb, flng, flnb, Crow, d_out);
}

// Round 5
// 287.759 us; speedup vs baseline: 1.1965x; 1.0385x over previous
//
#include <hip/hip_runtime.h>
#include <hip/hip_bf16.h>

// Problem constants (B=32, S=512, F=32, H=8, D=300, FH=32)
#define NB 32
#define NS 512
#define NF 32
#define NH 8
#define ND 300
#define NTOK (NB*NS)      // 16384 tokens
#define TPW 8             // tokens per wave (R2 frame: best measured)
#define WPB 2             // waves per block; wave-private LDS, zero barriers
#define TPB (TPW*WPB)     // 16 tokens per block -> grid 1024

#define L2E 1.4426950408889634f

// SoA plane offsets (in dwords) inside the workspace.
// R14: AoS 64B rows made every f-loop load a 64-distinct-line gather
// (L1/TA-serialized; R4's stall explosion). SoA planes make consecutive
// lanes read consecutive 16B/8B -> ideal coalesced pattern, 4x less TA work.
#define NFD (NF*ND)              // 9600 (f,d) entries
#define PA_OFF 0                 // uint4 per (f,d): P0..P3 (bf16 pairs A_k, B_k*L2E)
#define PB_OFF (NFD*4)           // uint4 per (f,d): P4..P7
#define CC_OFF (NFD*8)           // uint4 per (f,d): bcA, bcB*L2E, sg_ln_g, sg_ln_b
#define RR_OFF (NFD*12)          // uint2 per (f,d): rw, rb (folded residual)

using bf16 = __hip_bfloat16;
typedef float v2f __attribute__((ext_vector_type(2)));

__device__ __forceinline__ float rcpf_(float x){ return __builtin_amdgcn_rcpf(x); }
__device__ __forceinline__ float rsqf_(float x){ return __builtin_amdgcn_rsqf(x); }
__device__ __forceinline__ float sigm(float x){ return rcpf_(1.0f + __expf(-x)); }
// gate-B coefficients are pre-scaled by log2(e) in precompute -> exp2 directly
__device__ __forceinline__ float sigm2(float x){ return rcpf_(1.0f + __builtin_amdgcn_exp2f(-x)); }
__device__ __forceinline__ float eluf(float x){ return x > 0.0f ? x : __expf(x) - 1.0f; }

// packed fp32 FMA -> v_pk_fma_f32
__device__ __forceinline__ v2f fma2(v2f a, v2f b, v2f c){
    return __builtin_elementwise_fma(a, b, c);
}
__device__ __forceinline__ v2f fma2s(float s, v2f b, v2f c){
    return __builtin_elementwise_fma((v2f){s, s}, b, c);
}

template<int BF16>
__device__ __forceinline__ float ldf(const void* p, size_t i){
    if (BF16) return __bfloat162float(((const bf16*)p)[i]);
    return ((const float*)p)[i];
}
template<int BF16>
__device__ __forceinline__ void stf(void* p, size_t i, float v){
    if (BF16) ((bf16*)p)[i] = __float2bfloat16(v);
    else      ((float*)p)[i] = v;
}

// dtype test on a known-ones tensor: bf16 pair -> 0x3F803F80, fp32 -> 0x3F800000
__device__ __forceinline__ bool is_bf16(const void* ones){
    return *(const unsigned*)ones == 0x3F803F80u;
}

// bf16 pair (lo,hi) -> v2f {lo,hi}: 2 VALU ops
__device__ __forceinline__ v2f unpk(unsigned u){
    return (v2f){ __int_as_float((int)(u << 16)),
                  __int_as_float((int)(u & 0xFFFF0000u)) };
}
__device__ __forceinline__ unsigned pack_bf(float a, float b){
    bf16 ha = __float2bfloat16(a), hb = __float2bfloat16(b);
    return (unsigned)*(unsigned short*)&ha | ((unsigned)*(unsigned short*)&hb << 16);
}

// ---------------- DPP reductions (VALU pipe — keeps the LDS pipe free) ------
template<int CTRL>
__device__ __forceinline__ float dppadd(float v){
    return v + __int_as_float(__builtin_amdgcn_update_dpp(
        0, __float_as_int(v), CTRL, 0xF, 0xF, true));
}
template<int CTRL>
__device__ __forceinline__ float dppmax(float v){
    return fmaxf(v, __int_as_float(__builtin_amdgcn_update_dpp(
        __float_as_int(v), __float_as_int(v), CTRL, 0xF, 0xF, false)));
}
__device__ __forceinline__ float rlane(float v, int l){
    return __int_as_float(__builtin_amdgcn_readlane(__float_as_int(v), l));
}
__device__ __forceinline__ float wsum64(float v){
    v = dppadd<0x111>(v); v = dppadd<0x112>(v); v = dppadd<0x114>(v); v = dppadd<0x118>(v);
    v = dppadd<0x142>(v); v = dppadd<0x143>(v);
    return rlane(v, 63);
}
__device__ __forceinline__ float rsum32(float v){
    v = dppadd<0x111>(v); v = dppadd<0x112>(v); v = dppadd<0x114>(v); v = dppadd<0x118>(v);
    return rlane(v, 15) + rlane(v, 31);
}
__device__ __forceinline__ float rmax32(float v){
    v = dppmax<0x111>(v); v = dppmax<0x112>(v); v = dppmax<0x114>(v); v = dppmax<0x118>(v);
    return fmaxf(rlane(v, 15), rlane(v, 31));
}

// ---------------------------------------------------------------------------
// Precompute per-(f,d) coefficients into SoA planes (see offsets above):
//   PA/PB: 8 bf16 pairs (lo=A_k, hi=B_k*log2e)   [gate coeffs, folded fc2]
//   CC   : bcA, bcB*log2e, sg_ln_g, sg_ln_b (fp32)
//   RR   : rw, rb (fp32)  [residual folded: interp(pre)=x*rw+rb]
// ---------------------------------------------------------------------------
template<int BF16>
__device__ void precompute_body(const void* __restrict__ W2, const void* __restrict__ b2,
                                const void* __restrict__ Wg, const void* __restrict__ bg,
                                const void* __restrict__ sg_g, const void* __restrict__ sg_b,
                                const void* __restrict__ pre_w, const void* __restrict__ pre_b,
                                unsigned* __restrict__ Crow,
                                float* __restrict__ w2t, float* __restrict__ b2s,
                                float (*part)[64][18])
{
    const int tid  = threadIdx.x;
    const int lane = tid & 63;
    const int wv   = tid >> 6;            // 0..7: m-chunk
    const int f    = blockIdx.x & 31;     // 160 blocks = 32 f x 5 d-chunks
    const int c    = blockIdx.x >> 5;     // 0..4
    const int d    = c * 64 + lane;       // 0..319 (chunk 4 partially masked)
    const int dc   = d < 299 ? d : 299;   // clamp for loads (keeps Wg in-bounds)

    // stage W2 transposed [m][k] (fp32) + b2 for this f
    for (int idx = tid; idx < 2400; idx += 512) {
        int m = idx >> 3, k = idx & 7;
        w2t[idx] = ldf<BF16>(W2, (size_t)f * 2400 + (size_t)k * 300 + m);
    }
    if (tid < 300) b2s[tid] = ldf<BF16>(b2, (size_t)f * 300 + tid);
    __syncthreads();

    v2f aA01 = {0,0}, aA23 = {0,0}, aA45 = {0,0}, aA67 = {0,0};
    v2f aB01 = {0,0}, aB23 = {0,0}, aB45 = {0,0}, aB67 = {0,0};
    float bAa = 0.f, bBa = 0.f;

    const int m0 = (wv * 300) >> 3;
    const int m1 = ((wv + 1) * 300) >> 3;
    const size_t WgF = (size_t)f * 180000 + dc;
    #pragma unroll 4
    for (int m = m0; m < m1; ++m) {
        float wa = ldf<BF16>(Wg, WgF + (size_t)m * 600);        // coalesced across lanes
        float wb = ldf<BF16>(Wg, WgF + (size_t)m * 600 + 300);  // coalesced across lanes
        float4 wk0 = *(const float4*)(w2t + m * 8);             // k0..3 (broadcast)
        float4 wk1 = *(const float4*)(w2t + m * 8 + 4);         // k4..7 (broadcast)
        aA01 = fma2s(wa, (v2f){wk0.x, wk0.y}, aA01);
        aA23 = fma2s(wa, (v2f){wk0.z, wk0.w}, aA23);
        aA45 = fma2s(wa, (v2f){wk1.x, wk1.y}, aA45);
        aA67 = fma2s(wa, (v2f){wk1.z, wk1.w}, aA67);
        aB01 = fma2s(wb, (v2f){wk0.x, wk0.y}, aB01);
        aB23 = fma2s(wb, (v2f){wk0.z, wk0.w}, aB23);
        aB45 = fma2s(wb, (v2f){wk1.x, wk1.y}, aB45);
        aB67 = fma2s(wb, (v2f){wk1.z, wk1.w}, aB67);
        float b2v = b2s[m];
        bAa += b2v * wa;
        bBa += b2v * wb;
    }

    {
        float* p = part[wv][lane];
        p[0]  = aA01.x; p[1]  = aA01.y; p[2]  = aA23.x; p[3]  = aA23.y;
        p[4]  = aA45.x; p[5]  = aA45.y; p[6]  = aA67.x; p[7]  = aA67.y;
        p[8]  = aB01.x; p[9]  = aB01.y; p[10] = aB23.x; p[11] = aB23.y;
        p[12] = aB45.x; p[13] = aB45.y; p[14] = aB67.x; p[15] = aB67.y;
        p[16] = bAa;    p[17] = bBa;
    }
    __syncthreads();

    if (tid < 64 && d < 300) {
        float s[18];
        #pragma unroll
        for (int v = 0; v < 18; ++v) {
            float t0 = part[0][lane][v] + part[1][lane][v];
            float t1 = part[2][lane][v] + part[3][lane][v];
            float t2 = part[4][lane][v] + part[5][lane][v];
            float t3 = part[6][lane][v] + part[7][lane][v];
            s[v] = (t0 + t1) + (t2 + t3);
        }
        unsigned dw[12];
        #pragma unroll
        for (int k = 0; k < 8; ++k) dw[k] = pack_bf(s[k], s[8 + k] * L2E);
        dw[8]  = __float_as_uint(s[16] + ldf<BF16>(bg, (size_t)f * 600 + d));
        dw[9]  = __float_as_uint((s[17] + ldf<BF16>(bg, (size_t)f * 600 + d + 300)) * L2E);
        dw[10] = __float_as_uint(ldf<BF16>(sg_g, (size_t)f * 300 + d));
        dw[11] = __float_as_uint(ldf<BF16>(sg_b, (size_t)f * 300 + d));

        // residual fold: rw = interp(pre_w[f,:]) at d, rb = interp(pre_b[f,:])
        float pos = (float)d * (7.0f / 299.0f);
        int lo = (int)floorf(pos); lo = lo < 0 ? 0 : (lo > 6 ? 6 : lo);
        float fr = pos - (float)lo;
        float pwl = ldf<BF16>(pre_w, (size_t)f * 8 + lo);
        float pwh = ldf<BF16>(pre_w, (size_t)f * 8 + lo + 1);
        float pbl = ldf<BF16>(pre_b, (size_t)f * 8 + lo);
        float pbh = ldf<BF16>(pre_b, (size_t)f * 8 + lo + 1);
        unsigned rwu = __float_as_uint(pwl + fr * (pwh - pwl));
        unsigned rbu = __float_as_uint(pbl + fr * (pbh - pbl));

        // SoA plane writes (lane -> d consecutive: fully coalesced)
        const size_t fd = (size_t)f * ND + d;
        *(uint4*)(Crow + PA_OFF + fd * 4) = make_uint4(dw[0], dw[1], dw[2],  dw[3]);
        *(uint4*)(Crow + PB_OFF + fd * 4) = make_uint4(dw[4], dw[5], dw[6],  dw[7]);
        *(uint4*)(Crow + CC_OFF + fd * 4) = make_uint4(dw[8], dw[9], dw[10], dw[11]);
        *(uint2*)(Crow + RR_OFF + fd * 2) = make_uint2(rwu, rbu);
    }
}

__global__ void precompute_kernel(const void* __restrict__ W2, const void* __restrict__ b2,
                                  const void* __restrict__ Wg, const void* __restrict__ bg,
                                  const void* __restrict__ sg_g, const void* __restrict__ sg_b,
                                  const void* __restrict__ pre_w, const void* __restrict__ pre_b,
                                  unsigned* __restrict__ Crow)
{
    __shared__ float w2t[2400];          // W2 transposed [m][k], fp32
    __shared__ float b2s[300];
    __shared__ float part[8][64][18];    // per-wave partials
    if (is_bf16(sg_g))   // sg_ln_g is ones
        precompute_body<1>(W2, b2, Wg, bg, sg_g, sg_b, pre_w, pre_b, Crow, w2t, b2s, part);
    else
        precompute_body<0>(W2, b2, Wg, bg, sg_g, sg_b, pre_w, pre_b, Crow, w2t, b2s, part);
}

// ---------------------------------------------------------------------------
// Main kernel (R15): R2 frame — 16 tokens/block (2 waves x 8 tokens), zero
// barriers, wave-private LDS (24 KB/block). Hot-loop:
//   * SoA coefficient planes (coalesced lane-consecutive loads; R4's AoS rows
//     were 64-line gathers that saturated the L1/TA path)
//   * residual folded to x*rw+rb (x in 4 regs, readlane'd)
//   * i=4 specialization (mask only where d>=300 can occur)
// R3/R4 lesson: kernel is jointly VALU/L1-bound; cut BOTH streams.
// ---------------------------------------------------------------------------
template<int BF16>
__device__ void vsn_body(const void* __restrict__ x,
                         const void* __restrict__ pre_w, const void* __restrict__ pre_b,
                         const void* __restrict__ W1,    const void* __restrict__ b1,
                         const void* __restrict__ fl1w,  const void* __restrict__ fl1b,
                         const void* __restrict__ fl2w,  const void* __restrict__ fl2b,
                         const void* __restrict__ flgw,  const void* __restrict__ flgb,
                         const void* __restrict__ flng,  const void* __restrict__ flnb,
                         const unsigned* __restrict__ Crow,
                         void* __restrict__ d_out, float* preS_, unsigned* hS_)
{
    void* outMain = d_out;                                             // [B,S,D]
    void* outW    = (char*)d_out + (size_t)NTOK * ND * (BF16 ? 2 : 4); // [B,S,1,F]

    const int tid  = threadIdx.x;
    const int wave = tid >> 6;
    const int lane = tid & 63;
    const int tokBase = blockIdx.x * TPB + wave * TPW;   // this wave's 8 tokens

    float*    myPre = preS_ + wave * (TPW * 256);
    unsigned* myH   = hS_   + wave * (TPW * 128);        // 128 dwords (256 bf16)/token

    // ---- x in registers: xr_q holds x[tok = lane&7, f = q*8 + (lane>>3)] ----
    float xr0, xr1, xr2, xr3;
    {
        const int tx = lane & 7, fo = lane >> 3;
        const size_t bx = (size_t)(tokBase + tx) * NF + fo;
        xr0 = ldf<BF16>(x, bx);
        xr1 = ldf<BF16>(x, bx + 8);
        xr2 = ldf<BF16>(x, bx + 16);
        xr3 = ldf<BF16>(x, bx + 24);
    }

    // ---- Stage A: pre = x*pre_w + pre_b ----
    {
        float pw[4], pb[4];
        #pragma unroll
        for (int q = 0; q < 4; ++q) {
            pw[q] = ldf<BF16>(pre_w, 4 * lane + q);
            pb[q] = ldf<BF16>(pre_b, 4 * lane + q);
        }
        const int fidx = lane >> 1;
        #pragma unroll
        for (int t = 0; t < TPW; ++t) {
            float xv = ldf<BF16>(x, (size_t)(tokBase + t) * NF + fidx);
            float4 v;
            v.x = xv * pw[0] + pb[0];
            v.y = xv * pw[1] + pb[1];
            v.z = xv * pw[2] + pb[2];
            v.w = xv * pw[3] + pb[3];
            *(float4*)(&myPre[t * 256 + 4 * lane]) = v;
        }
    }

    // ---- Stage H: h = elu(pre @ W1 + b1), stored bf16-packed ----
    {
        const int f  = lane >> 1;
        const int kh = (lane & 1) * 4;
        float w1r[8][4], b1r[4];
        #pragma unroll
        for (int m = 0; m < 8; ++m)
            #pragma unroll
            for (int q = 0; q < 4; ++q)
                w1r[m][q] = ldf<BF16>(W1, (size_t)(f * 8 + m) * 8 + kh + q);
        #pragma unroll
        for (int q = 0; q < 4; ++q) b1r[q] = ldf<BF16>(b1, f * 8 + kh + q);

        #pragma unroll
        for (int t = 0; t < TPW; ++t) {
            float pr[8];
            float4 pA = *(const float4*)(&myPre[t * 256 + f * 8]);
            float4 pB = *(const float4*)(&myPre[t * 256 + f * 8 + 4]);
            pr[0]=pA.x; pr[1]=pA.y; pr[2]=pA.z; pr[3]=pA.w;
            pr[4]=pB.x; pr[5]=pB.y; pr[6]=pB.z; pr[7]=pB.w;
            float a[4] = {b1r[0], b1r[1], b1r[2], b1r[3]};
            #pragma unroll
            for (int m = 0; m < 8; ++m)
                #pragma unroll
                for (int q = 0; q < 4; ++q)
                    a[q] += pr[m] * w1r[m][q];
            uint2 hp;
            hp.x = pack_bf(eluf(a[0]), eluf(a[1]));
            hp.y = pack_bf(eluf(a[2]), eluf(a[3]));
            *(uint2*)(&myH[t * 128 + 2 * lane]) = hp;    // dwords 2l,2l+1 = cols 4l..4l+3
        }
    }

    // ---- Stage B: flattened GRN -> softmax weights (8 tokens/wave) ----
    const int jj = lane & 31;
    const int hB = lane >> 5;
    float wreg[TPW];
    {
        float f1b = (hB == 0) ? ldf<BF16>(fl1b, jj) : 0.0f;
        v2f p1v[TPW / 2];
        #pragma unroll
        for (int g = 0; g < TPW / 2; ++g) p1v[g] = (v2f){f1b, f1b};
        for (int kg = 0; kg < 32; ++kg) {
            const int kk = hB * 128 + kg * 4;
            float4 pr[TPW];
            #pragma unroll
            for (int t = 0; t < TPW; ++t)
                pr[t] = *(const float4*)(&myPre[t * 256 + kk]);
            float w0 = ldf<BF16>(fl1w, (size_t)(kk + 0) * 32 + jj);
            float w1 = ldf<BF16>(fl1w, (size_t)(kk + 1) * 32 + jj);
            float w2 = ldf<BF16>(fl1w, (size_t)(kk + 2) * 32 + jj);
            float w3 = ldf<BF16>(fl1w, (size_t)(kk + 3) * 32 + jj);
            #pragma unroll
            for (int g = 0; g < TPW / 2; ++g) {
                p1v[g] = fma2((v2f){pr[2*g].x, pr[2*g+1].x}, (v2f){w0, w0}, p1v[g]);
                p1v[g] = fma2((v2f){pr[2*g].y, pr[2*g+1].y}, (v2f){w1, w1}, p1v[g]);
                p1v[g] = fma2((v2f){pr[2*g].z, pr[2*g+1].z}, (v2f){w2, w2}, p1v[g]);
                p1v[g] = fma2((v2f){pr[2*g].w, pr[2*g+1].w}, (v2f){w3, w3}, p1v[g]);
            }
        }
        float fhv[TPW];
        #pragma unroll
        for (int t = 0; t < TPW; ++t) {
            float p1 = (t & 1) ? p1v[t >> 1].y : p1v[t >> 1].x;
            fhv[t] = eluf(p1 + __shfl_xor(p1, 32));
        }

        float p2[TPW];
        float f2b = ldf<BF16>(fl2b, jj);
        #pragma unroll
        for (int t = 0; t < TPW; ++t) p2[t] = f2b;
        #pragma unroll
        for (int k = 0; k < 32; ++k) {
            float wv = ldf<BF16>(fl2w, k * 32 + jj);
            #pragma unroll
            for (int t = 0; t < TPW; ++t) p2[t] += rlane(fhv[t], k) * wv;
        }
        float p3[TPW];
        float fgbv = ldf<BF16>(flgb, lane);
        #pragma unroll
        for (int t = 0; t < TPW; ++t) p3[t] = fgbv;
        #pragma unroll
        for (int k = 0; k < 32; ++k) {
            float wv = ldf<BF16>(flgw, k * 64 + lane);
            #pragma unroll
            for (int t = 0; t < TPW; ++t) p3[t] += rlane(p2[t], k) * wv;
        }

        float lng = ldf<BF16>(flng, jj), lnb = ldf<BF16>(flnb, jj);
        float posB = (float)jj * (255.0f / 31.0f);
        int loB = (int)floorf(posB); loB = loB < 0 ? 0 : (loB > 254 ? 254 : loB);
        float frB = posB - (float)loB;

        #pragma unroll
        for (int t = 0; t < TPW; ++t) {
            float fgA  = __shfl(p3[t], jj);
            float fgB  = __shfl(p3[t], jj + 32);
            float fglu = fgA * sigm(fgB);
            float pl = myPre[t * 256 + loB];
            float ph = myPre[t * 256 + loB + 1];
            float tv = fglu + pl + frB * (ph - pl);
            float S1 = rsum32(tv);
            float S2 = rsum32(tv * tv);
            float mean = S1 * (1.0f / 32.0f);
            float var  = fmaxf(S2 * (1.0f / 32.0f) - mean * mean, 0.0f);
            float rs   = rsqf_(var + 1e-5f);
            float wl   = (tv - mean) * rs * lng + lnb;
            float mx   = rmax32(wl);
            float e    = __expf(wl - mx);
            float ss   = rsum32(e);
            float wv   = e * rcpf_(ss);
            wreg[t] = wv;
            if (lane < 32) stf<BF16>(outW, (size_t)(tokBase + t) * NF + lane, wv);
        }
    }

    float acc[TPW][5];
    #pragma unroll
    for (int t = 0; t < TPW; ++t)
        #pragma unroll
        for (int i = 0; i < 5; ++i) acc[t][i] = 0.0f;

    // ---- feature loop: SoA coefficient planes (coalesced), t-outer epilogue ----
    for (int f = 0; f < NF; ++f) {
        // load this f's coefficients for this lane's 5 d values
        v2f  P[5][8];
        float bcA[5], bcB[5], lgv[5], lbv[5], rwv[5], rbv[5];
        #pragma unroll
        for (int i = 0; i < 5; ++i) {
            int d = i * 64 + lane;
            int dcl = d < ND ? d : ND - 1;
            const size_t fd = (size_t)f * ND + dcl;
            uint4 c0 = *(const uint4*)(Crow + PA_OFF + fd * 4);
            uint4 c1 = *(const uint4*)(Crow + PB_OFF + fd * 4);
            uint4 c2 = *(const uint4*)(Crow + CC_OFF + fd * 4);
            uint2 c3 = *(const uint2*)(Crow + RR_OFF + fd * 2);
            P[i][0] = unpk(c0.x); P[i][1] = unpk(c0.y);
            P[i][2] = unpk(c0.z); P[i][3] = unpk(c0.w);
            P[i][4] = unpk(c1.x); P[i][5] = unpk(c1.y);
            P[i][6] = unpk(c1.z); P[i][7] = unpk(c1.w);
            bcA[i] = __uint_as_float(c2.x);
            bcB[i] = __uint_as_float(c2.y);
            lgv[i] = __uint_as_float(c2.z);
            lbv[i] = __uint_as_float(c2.w);
            rwv[i] = __uint_as_float(c3.x);
            rbv[i] = __uint_as_float(c3.y);
        }

        float xq = (f < 8) ? xr0 : (f < 16) ? xr1 : (f < 24) ? xr2 : xr3;
        const int fl3 = (f & 7) << 3;

        #pragma unroll
        for (int t = 0; t < TPW; ++t) {
            uint4 hp = *(const uint4*)(&myH[t * 128 + f * 4]);   // 8 bf16 h values
            v2f h01 = unpk(hp.x), h23 = unpk(hp.y), h45 = unpk(hp.z), h67 = unpk(hp.w);
            float xv = rlane(xq, fl3 | t);                       // x[tok t, feature f]

            float tt[5], a1 = 0.f, a2 = 0.f;
            #pragma unroll
            for (int i = 0; i < 4; ++i) {          // d = i*64+lane <= 255: always valid
                v2f g = {bcA[i], bcB[i]};             // {gA, gB*log2e}
                g = fma2s(h01.x, P[i][0], g);
                g = fma2s(h01.y, P[i][1], g);
                g = fma2s(h23.x, P[i][2], g);
                g = fma2s(h23.y, P[i][3], g);
                g = fma2s(h45.x, P[i][4], g);
                g = fma2s(h45.y, P[i][5], g);
                g = fma2s(h67.x, P[i][6], g);
                g = fma2s(h67.y, P[i][7], g);
                float tv = fmaf(xv, rwv[i], rbv[i]) + g.x * sigm2(g.y);  // glu + residual
                tt[i] = tv; a1 += tv; a2 = fmaf(tv, tv, a2);
            }
            {                                       // i = 4: d = 256+lane, valid iff lane < 44
                v2f g = {bcA[4], bcB[4]};
                g = fma2s(h01.x, P[4][0], g);
                g = fma2s(h01.y, P[4][1], g);
                g = fma2s(h23.x, P[4][2], g);
                g = fma2s(h23.y, P[4][3], g);
                g = fma2s(h45.x, P[4][4], g);
                g = fma2s(h45.y, P[4][5], g);
                g = fma2s(h67.x, P[4][6], g);
                g = fma2s(h67.y, P[4][7], g);
                float tv = fmaf(xv, rwv[4], rbv[4]) + g.x * sigm2(g.y);
                tv = (lane < (ND - 256)) ? tv : 0.0f;
                tt[4] = tv; a1 += tv; a2 = fmaf(tv, tv, a2);
            }

            float S1 = wsum64(a1);
            float S2 = wsum64(a2);
            float mean = S1 * (1.0f / 300.0f);
            float var  = fmaxf(S2 * (1.0f / 300.0f) - mean * mean, 0.0f);
            float rs   = rsqf_(var + 1e-5f);
            float wf   = rlane(wreg[t], f);            // dynamic-uniform readlane
            float c1v  = wf * rs;
            float c2v  = -c1v * mean;
            // acc += wf*((tt-mean)*rs*lg + lb)  ==  fma(lg, fma(c1,tt,c2), fma(wf,lb,acc))
            #pragma unroll
            for (int i = 0; i < 4; ++i)
                acc[t][i] = fmaf(lgv[i], fmaf(c1v, tt[i], c2v), fmaf(wf, lbv[i], acc[t][i]));
            if (lane < (ND - 256))
                acc[t][4] = fmaf(lgv[4], fmaf(c1v, tt[4], c2v), fmaf(wf, lbv[4], acc[t][4]));
        }
    }

    // ---- write out ----
    #pragma unroll
    for (int t = 0; t < TPW; ++t) {
        const size_t tok = (size_t)tokBase + t;
        #pragma unroll
        for (int i = 0; i < 4; ++i)
            stf<BF16>(outMain, tok * ND + i * 64 + lane, acc[t][i]);
        if (lane < (ND - 256))
            stf<BF16>(outMain, tok * ND + 256 + lane, acc[t][4]);
    }
}

__launch_bounds__(128)
__global__ void vsn_main(const void* __restrict__ x,
                         const void* __restrict__ pre_w, const void* __restrict__ pre_b,
                         const void* __restrict__ W1,    const void* __restrict__ b1,
                         const void* __restrict__ fl1w,  const void* __restrict__ fl1b,
                         const void* __restrict__ fl2w,  const void* __restrict__ fl2b,
                         const void* __restrict__ flgw,  const void* __restrict__ flgb,
                         const void* __restrict__ flng,  const void* __restrict__ flnb,
                         const unsigned* __restrict__ Crow, void* __restrict__ d_out)
{
    __shared__ float    preS_[WPB * TPW * 256];   // 16 KB fp32
    __shared__ unsigned hS_[WPB * TPW * 128];     // 8 KB bf16-packed
    if (is_bf16(flng))   // fl_ln_g is ones
        vsn_body<1>(x, pre_w, pre_b, W1, b1, fl1w, fl1b, fl2w, fl2b,
                    flgw, flgb, flng, flnb, Crow, d_out, preS_, hS_);
    else
        vsn_body<0>(x, pre_w, pre_b, W1, b1, fl1w, fl1b, fl2w, fl2b,
                    flgw, flgb, flng, flnb, Crow, d_out, preS_, hS_);
}

extern "C" void kernel_launch(void* const* d_in, const int* in_sizes, int n_in,
                              void* d_out, int out_size, void* d_ws, size_t ws_size,
                              hipStream_t stream)
{
    const void* x     = d_in[0];
    const void* pre_w = d_in[1];
    const void* pre_b = d_in[2];
    const void* W1    = d_in[3];
    const void* b1    = d_in[4];
    const void* W2    = d_in[5];
    const void* b2    = d_in[6];
    const void* Wg    = d_in[7];
    const void* bg    = d_in[8];
    const void* sg_g  = d_in[9];
    const void* sg_b  = d_in[10];
    const void* fl1w  = d_in[11];
    const void* fl1b  = d_in[12];
    const void* fl2w  = d_in[13];
    const void* fl2b  = d_in[14];
    const void* flgw  = d_in[15];
    const void* flgb  = d_in[16];
    const void* flng  = d_in[17];
    const void* flnb  = d_in[18];

    unsigned* Crow = (unsigned*)d_ws;    // SoA planes: 14 dwords/(f,d) = 537.6 KB

    precompute_kernel<<<160, 512, 0, stream>>>(W2, b2, Wg, bg, sg_g, sg_b,
                                               pre_w, pre_b, Crow);

    vsn_main<<<NTOK / TPB, 128, 0, stream>>>(x, pre_w, pre_b, W1, b1,
        fl1w, fl1b, fl2w, fl2b, flgw, flgb, flng, flnb, Crow, d_out);
}